// Round 16
// baseline (3573.591 us; speedup 1.0000x reference)
//
#include <hip/hip_runtime.h>
#include <math.h>

#define NSITE 100
#define NOCC  50
#define DIM   128
#define KDET  4
#define NLDS  20          // columns 0..19 live in LDS during LU
#define LROW  21          // LDS row stride (odd -> conflict-free lane->bank)

// ---------------------------------------------------------------------------
// Wave64 max-reduction via DPP (VALU-only). row_shr 1/2/4/8 + bcast15 +
// bcast31; lane 63 ends with the global max.
// ---------------------------------------------------------------------------
__device__ __forceinline__ unsigned dpp_max64_to_lane63(unsigned x) {
  unsigned t;
  t = (unsigned)__builtin_amdgcn_update_dpp((int)x, (int)x, 0x111, 0xf, 0xf, false);
  x = x > t ? x : t;
  t = (unsigned)__builtin_amdgcn_update_dpp((int)x, (int)x, 0x112, 0xf, 0xf, false);
  x = x > t ? x : t;
  t = (unsigned)__builtin_amdgcn_update_dpp((int)x, (int)x, 0x114, 0xf, 0xf, false);
  x = x > t ? x : t;
  t = (unsigned)__builtin_amdgcn_update_dpp((int)x, (int)x, 0x118, 0xf, 0xf, false);
  x = x > t ? x : t;
  t = (unsigned)__builtin_amdgcn_update_dpp((int)x, (int)x, 0x142, 0xa, 0xf, false);
  x = x > t ? x : t;
  t = (unsigned)__builtin_amdgcn_update_dpp((int)x, (int)x, 0x143, 0xc, 0xf, false);
  x = x > t ? x : t;
  return x;
}

// ---------------------------------------------------------------------------
// R10-R15 RA model (measured, 6 configs): the allocator never holds ~50
// parked fp32 accumulators in VGPRs at >=5 waves/EU -- it spills to 32-40
// regardless of budget margin. Spill-free 8-wave residency needs demand
// <= ~48. So shrink the algorithmic state: LU columns 0..19 (only ~210 of
// 2500 total touches) live in a per-wave LDS tile; columns 20..49 (30 regs)
// stay in registers. GEMM in 5 fully-unrolled 10-column sweeps (R15 showed
// unroll-1 serializes SMEM latency); sweeps 1-2 write to LDS and die.
// Peak demand ~46. LDS 19KB/block -> 8 blocks/CU = 8 waves/EU.
// ---------------------------------------------------------------------------
#define REPA10(X) X(0) X(1) X(2) X(3) X(4) X(5) X(6) X(7) X(8) X(9)
#define REPB10(X) X(10) X(11) X(12) X(13) X(14) X(15) X(16) X(17) X(18) X(19)
#define REPC10(X) X(20) X(21) X(22) X(23) X(24) X(25) X(26) X(27) X(28) X(29)
#define REPD10(X) X(30) X(31) X(32) X(33) X(34) X(35) X(36) X(37) X(38) X(39)
#define REPE10(X) X(40) X(41) X(42) X(43) X(44) X(45) X(46) X(47) X(48) X(49)
// LDS-step outer (J=0..19) and inner (CC=0..19) copies (no macro recursion)
#define REP20A(X) X(0) X(1) X(2) X(3) X(4) X(5) X(6) X(7) X(8) X(9) \
  X(10) X(11) X(12) X(13) X(14) X(15) X(16) X(17) X(18) X(19)
#define REP20B(X) X(0) X(1) X(2) X(3) X(4) X(5) X(6) X(7) X(8) X(9) \
  X(10) X(11) X(12) X(13) X(14) X(15) X(16) X(17) X(18) X(19)
// reg-column copies: outer steps (J=20..49), inner updates, top-level
#define REP30A(X) X(20) X(21) X(22) X(23) X(24) X(25) X(26) X(27) X(28) X(29) \
  X(30) X(31) X(32) X(33) X(34) X(35) X(36) X(37) X(38) X(39) \
  X(40) X(41) X(42) X(43) X(44) X(45) X(46) X(47) X(48) X(49)
#define REP30B(X) X(20) X(21) X(22) X(23) X(24) X(25) X(26) X(27) X(28) X(29) \
  X(30) X(31) X(32) X(33) X(34) X(35) X(36) X(37) X(38) X(39) \
  X(40) X(41) X(42) X(43) X(44) X(45) X(46) X(47) X(48) X(49)
#define REP30C(X) X(20) X(21) X(22) X(23) X(24) X(25) X(26) X(27) X(28) X(29) \
  X(30) X(31) X(32) X(33) X(34) X(35) X(36) X(37) X(38) X(39) \
  X(40) X(41) X(42) X(43) X(44) X(45) X(46) X(47) X(48) X(49)

// One block per (batch, spin). Wave w handles determinant k=w.
// Lane r owns row r: cols 0..19 in its LDS tile row, cols 20..49 in regs.
__global__ __launch_bounds__(256)
__attribute__((amdgpu_waves_per_eu(8)))
void det_kernel(
    const int*   __restrict__ configs,   // (B,100) int32
    const float* __restrict__ tok,       // (4,128)
    const float* __restrict__ pos,       // (144,128)
    const float* __restrict__ W,         // (400,128)
    const float* __restrict__ bvec,      // (400,)
    double*      __restrict__ dets)      // (B,2,4,2)  {logdet, sign}
{
  const int b    = blockIdx.x;
  const int spin = blockIdx.y;

  __shared__ int cfg[NSITE];
  __shared__ int idx[NOCC];
  __shared__ int occl[NOCC];
  __shared__ int filll[NOCC];
  __shared__ int perm[4][NOCC];
  __shared__ float ldsm[4][51 * LROW];   // per-wave tile; row 50 = trash row

  const int tid = threadIdx.x;
  if (tid < NSITE) cfg[tid] = configs[(size_t)b * NSITE + tid];
  __syncthreads();

  // Occupied-index list per reference argsort semantics: all occupied sites
  // (ascending, capped 50) + smallest unoccupied fill, merged sorted.
  if (tid == 0) {
    int no = 0, nf = 0;
    for (int n = 0; n < NSITE; ++n) {
      int c = cfg[n];
      bool occ = (spin == 0) ? (c == 1 || c == 3) : (c == 2 || c == 3);
      if (occ) { if (no < NOCC) occl[no++]  = n; }
      else     { if (nf < NOCC) filll[nf++] = n; }
    }
    int need = NOCC - no; if (need < 0) need = 0;
    int i = 0, j = 0;
    for (int k = 0; k < NOCC; ++k) {
      bool takeocc = (i < no) && (j >= need || occl[i] < filll[j]);
      idx[k] = takeocc ? occl[i++] : filll[j++];
    }
  }
  __syncthreads();

  const int lane = tid & 63;
  const int wave = tid >> 6;
  const int wave_u  = __builtin_amdgcn_readfirstlane(wave);
  const int colbase = spin * 200 + wave_u * 50;          // uniform
  const float* Wb = W    + (size_t)colbase * DIM;        // uniform base
  const float* bb = bvec + colbase;

  const bool act  = (lane < NOCC);
  const int  site = idx[act ? lane : 0];
  const int  cc0  = cfg[site];
  const float4* tok4 = (const float4*)(tok + (size_t)cc0  * DIM);
  const float4* pos4 = (const float4*)(pos + (size_t)site * DIM);
  const float4* W4   = (const float4*)Wb;

  float* wbase = &ldsm[wave_u][0];
  const int rowid = act ? lane : 50;           // inactive lanes -> trash row
  float* myrow = wbase + rowid * LROW;

  #define DECLQ(i) float q##i = bb[i];
  #define GSTEP(i) { float4 w = W4[(i) * (DIM / 4) + d4]; \
    q##i = fmaf(h3, w.w, fmaf(h2, w.z, fmaf(h1, w.y, fmaf(h0, w.x, q##i)))); }
  #define WOUT(i)  myrow[i] = q##i;
  #define GBODY(REPX) \
    _Pragma("unroll") \
    for (int d4 = 0; d4 < DIM / 4; ++d4) { \
      float4 t = tok4[d4], pv = pos4[d4]; \
      const float h0 = t.x + pv.x, h1 = t.y + pv.y; \
      const float h2 = t.z + pv.z, h3 = t.w + pv.w; \
      REPX(GSTEP) \
    }

  // ---- GEMM sweeps 1-2: cols 0..19 -> LDS tile, registers freed ----
  { REPA10(DECLQ) GBODY(REPA10) REPA10(WOUT) }
  { REPB10(DECLQ) GBODY(REPB10) REPB10(WOUT) }

  // ---- GEMM sweeps 3-5: cols 20..49 stay in registers ----
  REP30B(DECLQ)
  GBODY(REPC10)
  GBODY(REPD10)
  GBODY(REPE10)
  #undef GBODY
  #undef WOUT
  #undef GSTEP
  #undef DECLQ

  // zero inactive lanes' reg columns (LDS trash row is masked via alive)
  #define ZEROQ(i) q##i = act ? q##i : 0.0f;
  REP30C(ZEROQ)
  #undef ZEROQ

  // ---- LU (fp32) with implicit partial pivoting -------------------------
  float  mant_prod = 1.0f;     // product of pivot mantissas in [1,2): < 2^50
  int    esum = 0, neg = 0, mystep = -1;
  unsigned alive = act ? 1u : 0u;

  // LDS-column update (CC in 0..19): own value + broadcast pivot value.
  // Lane p has mult=0 -> rewrites its own value (benign). Trash row 50 is
  // written by all inactive lanes (same addr, don't care).
  #define UPDL(CC) if ((CC) > cJ) { \
      myrow[CC] = fmaf(-mult, prow[CC], myrow[CC]); }
  // Register-column update (CC in 20..49), always CC > J for J < 20.
  #define UPDR(CC) { \
      const float pc = __int_as_float( \
          __builtin_amdgcn_readlane(__float_as_int(q##CC), p)); \
      q##CC = fmaf(-mult, pc, q##CC); }
  #define LUS_LDS(J) { \
    const float ownj = myrow[J]; \
    const unsigned ab = __float_as_uint(ownj) & 0x7FFFFFFFu; \
    unsigned key = alive ? ((ab & ~63u) | (unsigned)lane) : 0u; \
    key = dpp_max64_to_lane63(key); \
    const int p = __builtin_amdgcn_readlane((int)key, 63) & 63; \
    const float* prow = wbase + p * LROW; \
    const float piv = prow[J]; \
    const unsigned pb = __float_as_uint(piv); \
    esum += (int)((pb >> 23) & 0xFFu) - 127; \
    neg  += (int)(pb >> 31); \
    mant_prod *= __uint_as_float((pb & 0x007FFFFFu) | 0x3F800000u); \
    if (lane == p) mystep = (J); \
    alive &= (lane != p) ? 1u : 0u; \
    const float rp = (piv != 0.0f) ? 1.0f / piv : 0.0f; \
    const float mult = alive ? ownj * rp : 0.0f; \
    const int cJ = (J); \
    REP20B(UPDL) \
    REP30B(UPDR) \
  }
  REP20A(LUS_LDS)
  #undef LUS_LDS
  #undef UPDL
  #undef UPDR

  #define UPD2(CC) if ((CC) > cJ) { \
      const float pc = __int_as_float( \
          __builtin_amdgcn_readlane(__float_as_int(q##CC), p)); \
      q##CC = fmaf(-mult, pc, q##CC); }
  #define LUS_REG(J) { \
    const unsigned ab = __float_as_uint(q##J) & 0x7FFFFFFFu; \
    unsigned key = alive ? ((ab & ~63u) | (unsigned)lane) : 0u; \
    key = dpp_max64_to_lane63(key); \
    const int p = __builtin_amdgcn_readlane((int)key, 63) & 63; \
    const float piv = __int_as_float( \
        __builtin_amdgcn_readlane(__float_as_int(q##J), p)); \
    const unsigned pb = __float_as_uint(piv); \
    esum += (int)((pb >> 23) & 0xFFu) - 127; \
    neg  += (int)(pb >> 31); \
    mant_prod *= __uint_as_float((pb & 0x007FFFFFu) | 0x3F800000u); \
    if (lane == p) mystep = (J); \
    alive &= (lane != p) ? 1u : 0u; \
    const float rp = (piv != 0.0f) ? 1.0f / piv : 0.0f; \
    const float mult = alive ? q##J * rp : 0.0f; \
    const int cJ = (J); \
    REP30C(UPD2) \
  }
  REP30A(LUS_REG)
  #undef LUS_REG
  #undef UPD2

  const double logdet =
      log((double)mant_prod) + (double)esum * 0.6931471805599453;

  // permutation parity: perm[step] = lane chosen at that step (LDS)
  if (mystep >= 0) perm[wave][mystep] = lane;
  __syncthreads();
  int pj  = perm[wave][act ? lane : 0];
  int inv = 0;
  for (int i = 0; i < NOCC; ++i) {
    int pi = perm[wave][i];
    inv += (act && i < lane && pi > pj) ? 1 : 0;
  }
  #pragma unroll
  for (int m = 32; m >= 1; m >>= 1) inv += __shfl_xor(inv, m, 64);

  const int sgn = ((neg + inv) & 1) ? -1 : 1;
  if (lane == 0) {
    size_t o = (((size_t)b * 2 + spin) * KDET + wave) * 2;
    dets[o]     = logdet;
    dets[o + 1] = (double)sgn;
  }
}

// PLANAR complex64 output: out[0..B) = log_abs (real), out[B..2B) = phase (imag)
__global__ __launch_bounds__(256) void combine_kernel(
    const double* __restrict__ dets, float* __restrict__ out, int B)
{
  int b = blockIdx.x * blockDim.x + threadIdx.x;
  if (b >= B) return;
  const double* du = dets + ((size_t)b * 2 + 0) * KDET * 2;
  const double* dd = dets + ((size_t)b * 2 + 1) * KDET * 2;
  double t[KDET], s[KDET], m = -1e300;
  #pragma unroll
  for (int k = 0; k < KDET; ++k) {
    t[k] = du[2 * k] + dd[2 * k];
    s[k] = du[2 * k + 1] * dd[2 * k + 1];
    if (t[k] > m) m = t[k];
  }
  double sum = 0.0;
  #pragma unroll
  for (int k = 0; k < KDET; ++k) {
    if (t[k] > -1e290) sum += s[k] * exp(t[k] - m);
  }
  double p  = (m > -1e290) ? exp(m) * fabs(sum) : 0.0;
  double la = log(p + 1e-30);                    // reproduce ref clamp exactly
  float phase = (sum >= 0.0) ? 0.0f : 3.14159265358979f;
  out[b]     = (float)la;
  out[B + b] = phase;
}

extern "C" void kernel_launch(void* const* d_in, const int* in_sizes, int n_in,
                              void* d_out, int out_size, void* d_ws, size_t ws_size,
                              hipStream_t stream) {
  const int*   configs = (const int*)  d_in[0];
  const float* tok     = (const float*)d_in[1];
  const float* pos     = (const float*)d_in[2];
  const float* W       = (const float*)d_in[3];
  const float* bv      = (const float*)d_in[4];
  double* dets = (double*)d_ws;            // needs B*2*4*2*8 = 256 KB
  const int B = in_sizes[0] / NSITE;

  dim3 grid(B, 2);
  det_kernel<<<grid, 256, 0, stream>>>(configs, tok, pos, W, bv, dets);
  combine_kernel<<<(B + 255) / 256, 256, 0, stream>>>(dets, (float*)d_out, B);
}

// Round 17
// 560.244 us; speedup vs baseline: 6.3786x; 6.3786x over previous
//
#include <hip/hip_runtime.h>
#include <math.h>

#define NSITE 100
#define NOCC  50
#define DIM   128
#define KDET  4

// ---------------------------------------------------------------------------
// Wave64 max-reduction via DPP (VALU-only). row_shr 1/2/4/8 + bcast15 +
// bcast31; lane 63 ends with the global max.
// ---------------------------------------------------------------------------
__device__ __forceinline__ unsigned dpp_max64_to_lane63(unsigned x) {
  unsigned t;
  t = (unsigned)__builtin_amdgcn_update_dpp((int)x, (int)x, 0x111, 0xf, 0xf, false);
  x = x > t ? x : t;
  t = (unsigned)__builtin_amdgcn_update_dpp((int)x, (int)x, 0x112, 0xf, 0xf, false);
  x = x > t ? x : t;
  t = (unsigned)__builtin_amdgcn_update_dpp((int)x, (int)x, 0x114, 0xf, 0xf, false);
  x = x > t ? x : t;
  t = (unsigned)__builtin_amdgcn_update_dpp((int)x, (int)x, 0x118, 0xf, 0xf, false);
  x = x > t ? x : t;
  t = (unsigned)__builtin_amdgcn_update_dpp((int)x, (int)x, 0x142, 0xa, 0xf, false);
  x = x > t ? x : t;
  t = (unsigned)__builtin_amdgcn_update_dpp((int)x, (int)x, 0x143, 0xc, 0xf, false);
  x = x > t ? x : t;
  return x;
}

// ---------------------------------------------------------------------------
// UNIFIED-FILE MODEL (explains R8-R16): real budget = (VGPR+AGPR) =
// 512/waves_per_eu; VGPR_Count excludes AGPRs. Parked accumulators overflow
// to AGPRs cheaply (no memory traffic -- R15: VGPR=40, WRITE=256KB);
// HBM scratch churn appears only when demand > combined budget (R12/14/16
// at (8): budget 64 < ~75 -> 44MB..3.4GB traffic).
// Demand here: 50 parked q + ~20-25 in-flight (W float4s, tok/pos, h)
// = ~70-75 -> waves_per_eu(6), budget 85, 75% occupancy.
// GEMM: 5 groups of 10 columns, separate d4 loops, DEFAULT unrolling
// (R15's unroll-1 serialized SMEM latency -> VALUBusy 36%).
// ---------------------------------------------------------------------------
#define REPA(X) X(0) X(1) X(2) X(3) X(4) X(5) X(6) X(7) X(8) X(9) \
  X(10) X(11) X(12) X(13) X(14) X(15) X(16) X(17) X(18) X(19) \
  X(20) X(21) X(22) X(23) X(24) X(25) X(26) X(27) X(28) X(29) \
  X(30) X(31) X(32) X(33) X(34) X(35) X(36) X(37) X(38) X(39) \
  X(40) X(41) X(42) X(43) X(44) X(45) X(46) X(47) X(48) X(49)
#define REPB(X) X(0) X(1) X(2) X(3) X(4) X(5) X(6) X(7) X(8) X(9) \
  X(10) X(11) X(12) X(13) X(14) X(15) X(16) X(17) X(18) X(19) \
  X(20) X(21) X(22) X(23) X(24) X(25) X(26) X(27) X(28) X(29) \
  X(30) X(31) X(32) X(33) X(34) X(35) X(36) X(37) X(38) X(39) \
  X(40) X(41) X(42) X(43) X(44) X(45) X(46) X(47) X(48) X(49)

// One block per (batch, spin). Wave w handles determinant k=w.
// Lane r owns row r of phi in 50 named fp32 registers (r < 50).
__global__ __launch_bounds__(256)
__attribute__((amdgpu_waves_per_eu(6)))
void det_kernel(
    const int*   __restrict__ configs,   // (B,100) int32
    const float* __restrict__ tok,       // (4,128)
    const float* __restrict__ pos,       // (144,128)
    const float* __restrict__ W,         // (400,128)
    const float* __restrict__ bvec,      // (400,)
    double*      __restrict__ dets)      // (B,2,4,2)  {logdet, sign}
{
  const int b    = blockIdx.x;
  const int spin = blockIdx.y;

  __shared__ int cfg[NSITE];
  __shared__ int idx[NOCC];
  __shared__ int occl[NOCC];
  __shared__ int filll[NOCC];
  __shared__ int perm[4][NOCC];

  const int tid = threadIdx.x;
  if (tid < NSITE) cfg[tid] = configs[(size_t)b * NSITE + tid];
  __syncthreads();

  // Occupied-index list per reference argsort semantics: all occupied sites
  // (ascending, capped 50) + smallest unoccupied fill, merged sorted.
  if (tid == 0) {
    int no = 0, nf = 0;
    for (int n = 0; n < NSITE; ++n) {
      int c = cfg[n];
      bool occ = (spin == 0) ? (c == 1 || c == 3) : (c == 2 || c == 3);
      if (occ) { if (no < NOCC) occl[no++]  = n; }
      else     { if (nf < NOCC) filll[nf++] = n; }
    }
    int need = NOCC - no; if (need < 0) need = 0;
    int i = 0, j = 0;
    for (int k = 0; k < NOCC; ++k) {
      bool takeocc = (i < no) && (j >= need || occl[i] < filll[j]);
      idx[k] = takeocc ? occl[i++] : filll[j++];
    }
  }
  __syncthreads();

  const int lane = tid & 63;
  const int wave = tid >> 6;
  const int wave_u  = __builtin_amdgcn_readfirstlane(wave);
  const int colbase = spin * 200 + wave_u * 50;          // uniform
  const float* Wb = W    + (size_t)colbase * DIM;        // uniform base
  const float* bb = bvec + colbase;

  const bool act  = (lane < NOCC);
  const int  site = idx[act ? lane : 0];
  const int  cc0  = cfg[site];
  const float4* tok4 = (const float4*)(tok + (size_t)cc0  * DIM);
  const float4* pos4 = (const float4*)(pos + (size_t)site * DIM);
  const float4* W4   = (const float4*)Wb;

  // ---- GEMM (fp32), 5 groups of 10 columns; each group re-walks the
  //      L1-hot tok/pos vectors; default unrolling for latency overlap ----
  #define DECLQ(i) float q##i = bb[i];
  REPB(DECLQ)
  #undef DECLQ

  #define GSTEP(i) { float4 w = W4[(i) * (DIM / 4) + d4]; \
    q##i = fmaf(h3, w.w, fmaf(h2, w.z, fmaf(h1, w.y, fmaf(h0, w.x, q##i)))); }
  #define GRP10(i0, i1, i2, i3, i4, i5, i6, i7, i8, i9) \
    for (int d4 = 0; d4 < DIM / 4; ++d4) { \
      float4 t = tok4[d4], pv = pos4[d4]; \
      const float h0 = t.x + pv.x, h1 = t.y + pv.y; \
      const float h2 = t.z + pv.z, h3 = t.w + pv.w; \
      GSTEP(i0) GSTEP(i1) GSTEP(i2) GSTEP(i3) GSTEP(i4) \
      GSTEP(i5) GSTEP(i6) GSTEP(i7) GSTEP(i8) GSTEP(i9) \
    }
  GRP10(0, 1, 2, 3, 4, 5, 6, 7, 8, 9)
  GRP10(10, 11, 12, 13, 14, 15, 16, 17, 18, 19)
  GRP10(20, 21, 22, 23, 24, 25, 26, 27, 28, 29)
  GRP10(30, 31, 32, 33, 34, 35, 36, 37, 38, 39)
  GRP10(40, 41, 42, 43, 44, 45, 46, 47, 48, 49)
  #undef GRP10
  #undef GSTEP

  // zero inactive lanes so they never win the pivot and updates stay benign
  #define ZEROQ(i) q##i = act ? q##i : 0.0f;
  REPB(ZEROQ)
  #undef ZEROQ

  // ---- LU (fp32, in place on q) with implicit partial pivoting ----------
  float  mant_prod = 1.0f;     // product of pivot mantissas in [1,2): < 2^50
  int    esum = 0, neg = 0, mystep = -1;
  unsigned alive = act ? 1u : 0u;

  #define UPD(CC) if ((CC) > cJ) { \
      const float pc = __int_as_float( \
          __builtin_amdgcn_readlane(__float_as_int(q##CC), p)); \
      q##CC = fmaf(-mult, pc, q##CC); }
  #define LUS(J) { \
    const unsigned ab = __float_as_uint(q##J) & 0x7FFFFFFFu; \
    unsigned key = alive ? ((ab & ~63u) | (unsigned)lane) : 0u; \
    key = dpp_max64_to_lane63(key); \
    const int p = __builtin_amdgcn_readlane((int)key, 63) & 63; \
    const float piv = __int_as_float( \
        __builtin_amdgcn_readlane(__float_as_int(q##J), p)); \
    const unsigned pb = __float_as_uint(piv); \
    esum += (int)((pb >> 23) & 0xFFu) - 127; \
    neg  += (int)(pb >> 31); \
    mant_prod *= __uint_as_float((pb & 0x007FFFFFu) | 0x3F800000u); \
    if (lane == p) mystep = (J); \
    alive &= (lane != p) ? 1u : 0u; \
    const float rp = (piv != 0.0f) ? 1.0f / piv : 0.0f; \
    const float mult = alive ? q##J * rp : 0.0f; \
    const int cJ = (J); \
    REPB(UPD) \
  }
  REPA(LUS)
  #undef LUS
  #undef UPD

  const double logdet =
      log((double)mant_prod) + (double)esum * 0.6931471805599453;

  // permutation parity: perm[step] = lane chosen at that step (LDS)
  if (mystep >= 0) perm[wave][mystep] = lane;
  __syncthreads();
  int pj  = perm[wave][act ? lane : 0];
  int inv = 0;
  for (int i = 0; i < NOCC; ++i) {
    int pi = perm[wave][i];
    inv += (act && i < lane && pi > pj) ? 1 : 0;
  }
  #pragma unroll
  for (int m = 32; m >= 1; m >>= 1) inv += __shfl_xor(inv, m, 64);

  const int sgn = ((neg + inv) & 1) ? -1 : 1;
  if (lane == 0) {
    size_t o = (((size_t)b * 2 + spin) * KDET + wave) * 2;
    dets[o]     = logdet;
    dets[o + 1] = (double)sgn;
  }
}

// PLANAR complex64 output: out[0..B) = log_abs (real), out[B..2B) = phase (imag)
__global__ __launch_bounds__(256) void combine_kernel(
    const double* __restrict__ dets, float* __restrict__ out, int B)
{
  int b = blockIdx.x * blockDim.x + threadIdx.x;
  if (b >= B) return;
  const double* du = dets + ((size_t)b * 2 + 0) * KDET * 2;
  const double* dd = dets + ((size_t)b * 2 + 1) * KDET * 2;
  double t[KDET], s[KDET], m = -1e300;
  #pragma unroll
  for (int k = 0; k < KDET; ++k) {
    t[k] = du[2 * k] + dd[2 * k];
    s[k] = du[2 * k + 1] * dd[2 * k + 1];
    if (t[k] > m) m = t[k];
  }
  double sum = 0.0;
  #pragma unroll
  for (int k = 0; k < KDET; ++k) {
    if (t[k] > -1e290) sum += s[k] * exp(t[k] - m);
  }
  double p  = (m > -1e290) ? exp(m) * fabs(sum) : 0.0;
  double la = log(p + 1e-30);                    // reproduce ref clamp exactly
  float phase = (sum >= 0.0) ? 0.0f : 3.14159265358979f;
  out[b]     = (float)la;
  out[B + b] = phase;
}

extern "C" void kernel_launch(void* const* d_in, const int* in_sizes, int n_in,
                              void* d_out, int out_size, void* d_ws, size_t ws_size,
                              hipStream_t stream) {
  const int*   configs = (const int*)  d_in[0];
  const float* tok     = (const float*)d_in[1];
  const float* pos     = (const float*)d_in[2];
  const float* W       = (const float*)d_in[3];
  const float* bv      = (const float*)d_in[4];
  double* dets = (double*)d_ws;            // needs B*2*4*2*8 = 256 KB
  const int B = in_sizes[0] / NSITE;

  dim3 grid(B, 2);
  det_kernel<<<grid, 256, 0, stream>>>(configs, tok, pos, W, bv, dets);
  combine_kernel<<<(B + 255) / 256, 256, 0, stream>>>(dets, (float*)d_out, B);
}

// Round 18
// 254.936 us; speedup vs baseline: 14.0176x; 2.1976x over previous
//
#include <hip/hip_runtime.h>
#include <math.h>

#define NSITE 100
#define NOCC  50
#define DIM   128
#define KDET  4
#define NTAB  400                         // K*(N_UP+N_DOWN)
#define TP_FLOATS ((4 + 144) * NTAB)      // T then P' in ws

// ---------------------------------------------------------------------------
// R18 ALGORITHMIC COLLAPSE: phi[r][j] = tok[c]·W_j + pos[s]·W_j + b_j and
// tok/pos/W are batch-independent inputs -> precompute T[4][400] and
// P'[144][400] = pos·W + b once (~15us, 237KB). The per-batch 10.5 GFLOP
// GEMM becomes 2 loads + 1 add per element. Per-wave VALU: ~39K -> ~9K cyc
// (R10-R17 showed tuning alone floors at ~430us; the work had to shrink).
// ---------------------------------------------------------------------------

// Wave64 max-reduction via DPP (VALU-only). Lane 63 ends with global max.
__device__ __forceinline__ unsigned dpp_max64_to_lane63(unsigned x) {
  unsigned t;
  t = (unsigned)__builtin_amdgcn_update_dpp((int)x, (int)x, 0x111, 0xf, 0xf, false);
  x = x > t ? x : t;
  t = (unsigned)__builtin_amdgcn_update_dpp((int)x, (int)x, 0x112, 0xf, 0xf, false);
  x = x > t ? x : t;
  t = (unsigned)__builtin_amdgcn_update_dpp((int)x, (int)x, 0x114, 0xf, 0xf, false);
  x = x > t ? x : t;
  t = (unsigned)__builtin_amdgcn_update_dpp((int)x, (int)x, 0x118, 0xf, 0xf, false);
  x = x > t ? x : t;
  t = (unsigned)__builtin_amdgcn_update_dpp((int)x, (int)x, 0x142, 0xa, 0xf, false);
  x = x > t ? x : t;
  t = (unsigned)__builtin_amdgcn_update_dpp((int)x, (int)x, 0x143, 0xc, 0xf, false);
  x = x > t ? x : t;
  return x;
}

#define REPA(X) X(0) X(1) X(2) X(3) X(4) X(5) X(6) X(7) X(8) X(9) \
  X(10) X(11) X(12) X(13) X(14) X(15) X(16) X(17) X(18) X(19) \
  X(20) X(21) X(22) X(23) X(24) X(25) X(26) X(27) X(28) X(29) \
  X(30) X(31) X(32) X(33) X(34) X(35) X(36) X(37) X(38) X(39) \
  X(40) X(41) X(42) X(43) X(44) X(45) X(46) X(47) X(48) X(49)
#define REPB(X) X(0) X(1) X(2) X(3) X(4) X(5) X(6) X(7) X(8) X(9) \
  X(10) X(11) X(12) X(13) X(14) X(15) X(16) X(17) X(18) X(19) \
  X(20) X(21) X(22) X(23) X(24) X(25) X(26) X(27) X(28) X(29) \
  X(30) X(31) X(32) X(33) X(34) X(35) X(36) X(37) X(38) X(39) \
  X(40) X(41) X(42) X(43) X(44) X(45) X(46) X(47) X(48) X(49)

// ---- Precompute: T[c][j] = tok[c].W_j ; P'[s][j] = pos[s].W_j + b_j ------
__global__ __launch_bounds__(256) void tp_kernel(
    const float* __restrict__ tok, const float* __restrict__ pos,
    const float* __restrict__ W,   const float* __restrict__ bvec,
    float* __restrict__ T, float* __restrict__ P)
{
  const int gid = blockIdx.x * 256 + threadIdx.x;
  if (gid >= 148 * NTAB) return;
  const int row = gid / NTAB;
  const int col = gid - row * NTAB;
  const float4* h4 = (const float4*)((row < 4) ? (tok + (size_t)row * DIM)
                                               : (pos + (size_t)(row - 4) * DIM));
  const float4* w4 = (const float4*)(W + (size_t)col * DIM);
  float acc = 0.0f;
  #pragma unroll
  for (int i = 0; i < DIM / 4; ++i) {
    float4 a = h4[i], b = w4[i];
    acc = fmaf(a.x, b.x, acc);
    acc = fmaf(a.y, b.y, acc);
    acc = fmaf(a.z, b.z, acc);
    acc = fmaf(a.w, b.w, acc);
  }
  if (row < 4) T[(size_t)row * NTAB + col] = acc;
  else         P[(size_t)(row - 4) * NTAB + col] = acc + bvec[col];
}

// One block per (batch, spin). Wave w handles determinant k=w.
// Lane r owns row r of phi in 50 named fp32 registers (r < 50).
// waves_per_eu(7): budget 73 vs demand ~62 (50 q + ~12 transients) --
// 15% margin, the measured-safe RA regime; 7 waves/EU residency.
__global__ __launch_bounds__(256)
__attribute__((amdgpu_waves_per_eu(7)))
void det_kernel(
    const int*   __restrict__ configs,   // (B,100) int32
    const float* __restrict__ T,         // (4,400)
    const float* __restrict__ P,         // (144,400)  includes bias
    double*      __restrict__ dets)      // (B,2,4,2)  {logdet, sign}
{
  const int b    = blockIdx.x;
  const int spin = blockIdx.y;

  __shared__ int cfg[NSITE];
  __shared__ int idx[NOCC];
  __shared__ int occl[NOCC];
  __shared__ int filll[NOCC];
  __shared__ int perm[4][NOCC];

  const int tid = threadIdx.x;
  if (tid < NSITE) cfg[tid] = configs[(size_t)b * NSITE + tid];
  __syncthreads();

  // Occupied-index list per reference argsort semantics: all occupied sites
  // (ascending, capped 50) + smallest unoccupied fill, merged sorted.
  if (tid == 0) {
    int no = 0, nf = 0;
    for (int n = 0; n < NSITE; ++n) {
      int c = cfg[n];
      bool occ = (spin == 0) ? (c == 1 || c == 3) : (c == 2 || c == 3);
      if (occ) { if (no < NOCC) occl[no++]  = n; }
      else     { if (nf < NOCC) filll[nf++] = n; }
    }
    int need = NOCC - no; if (need < 0) need = 0;
    int i = 0, j = 0;
    for (int k = 0; k < NOCC; ++k) {
      bool takeocc = (i < no) && (j >= need || occl[i] < filll[j]);
      idx[k] = takeocc ? occl[i++] : filll[j++];
    }
  }
  __syncthreads();

  const int lane = tid & 63;
  const int wave = tid >> 6;
  const int wave_u  = __builtin_amdgcn_readfirstlane(wave);
  const int colbase = spin * 200 + wave_u * 50;          // uniform

  const bool act  = (lane < NOCC);
  const int  site = idx[act ? lane : 0];
  const int  cc0  = cfg[site];
  // colbase is a multiple of 50 -> byte offset multiple of 200 -> 8-aligned
  // (NOT 16): use float2 loads.
  const float2* T2 = (const float2*)(T + (size_t)cc0  * NTAB + colbase);
  const float2* P2 = (const float2*)(P + (size_t)site * NTAB + colbase);

  // ---- assemble phi row: q_j = T[c][cb+j] + P'[site][cb+j] ----
  #define DECLQ(i) float q##i;
  REPB(DECLQ)
  #undef DECLQ
  // groups of 12 + sched_barrier(0) to bound in-flight loads (keep peak
  // register demand under the 73 budget; R14/R16 showed the RA melts down
  // when hoisted loads push demand past budget)
  #define LQ(i0, i1) { float2 a = T2[(i0) / 2], c = P2[(i0) / 2]; \
      q##i0 = a.x + c.x; q##i1 = a.y + c.y; }
  LQ(0, 1)  LQ(2, 3)  LQ(4, 5)  LQ(6, 7)  LQ(8, 9)  LQ(10, 11)
  __builtin_amdgcn_sched_barrier(0);
  LQ(12, 13) LQ(14, 15) LQ(16, 17) LQ(18, 19) LQ(20, 21) LQ(22, 23)
  __builtin_amdgcn_sched_barrier(0);
  LQ(24, 25) LQ(26, 27) LQ(28, 29) LQ(30, 31) LQ(32, 33) LQ(34, 35)
  __builtin_amdgcn_sched_barrier(0);
  LQ(36, 37) LQ(38, 39) LQ(40, 41) LQ(42, 43) LQ(44, 45) LQ(46, 47)
  __builtin_amdgcn_sched_barrier(0);
  LQ(48, 49)
  #undef LQ

  // zero inactive lanes so they never win the pivot and updates stay benign
  #define ZEROQ(i) q##i = act ? q##i : 0.0f;
  REPB(ZEROQ)
  #undef ZEROQ

  // ---- LU (fp32, in place on q) with implicit partial pivoting ----------
  float  mant_prod = 1.0f;     // product of pivot mantissas in [1,2): < 2^50
  int    esum = 0, neg = 0, mystep = -1;
  unsigned alive = act ? 1u : 0u;

  #define UPD(CC) if ((CC) > cJ) { \
      const float pc = __int_as_float( \
          __builtin_amdgcn_readlane(__float_as_int(q##CC), p)); \
      q##CC = fmaf(-mult, pc, q##CC); }
  #define LUS(J) { \
    const unsigned ab = __float_as_uint(q##J) & 0x7FFFFFFFu; \
    unsigned key = alive ? ((ab & ~63u) | (unsigned)lane) : 0u; \
    key = dpp_max64_to_lane63(key); \
    const int p = __builtin_amdgcn_readlane((int)key, 63) & 63; \
    const float piv = __int_as_float( \
        __builtin_amdgcn_readlane(__float_as_int(q##J), p)); \
    const unsigned pb = __float_as_uint(piv); \
    esum += (int)((pb >> 23) & 0xFFu) - 127; \
    neg  += (int)(pb >> 31); \
    mant_prod *= __uint_as_float((pb & 0x007FFFFFu) | 0x3F800000u); \
    if (lane == p) mystep = (J); \
    alive &= (lane != p) ? 1u : 0u; \
    const float rp = (piv != 0.0f) ? 1.0f / piv : 0.0f; \
    const float mult = alive ? q##J * rp : 0.0f; \
    const int cJ = (J); \
    REPB(UPD) \
  }
  REPA(LUS)
  #undef LUS
  #undef UPD

  const double logdet =
      log((double)mant_prod) + (double)esum * 0.6931471805599453;

  // permutation parity: perm[step] = lane chosen at that step (LDS)
  if (mystep >= 0) perm[wave][mystep] = lane;
  __syncthreads();
  int pj  = perm[wave][act ? lane : 0];
  int inv = 0;
  for (int i = 0; i < NOCC; ++i) {
    int pi = perm[wave][i];
    inv += (act && i < lane && pi > pj) ? 1 : 0;
  }
  #pragma unroll
  for (int m = 32; m >= 1; m >>= 1) inv += __shfl_xor(inv, m, 64);

  const int sgn = ((neg + inv) & 1) ? -1 : 1;
  if (lane == 0) {
    size_t o = (((size_t)b * 2 + spin) * KDET + wave) * 2;
    dets[o]     = logdet;
    dets[o + 1] = (double)sgn;
  }
}

// PLANAR complex64 output: out[0..B) = log_abs (real), out[B..2B) = phase (imag)
__global__ __launch_bounds__(256) void combine_kernel(
    const double* __restrict__ dets, float* __restrict__ out, int B)
{
  int b = blockIdx.x * blockDim.x + threadIdx.x;
  if (b >= B) return;
  const double* du = dets + ((size_t)b * 2 + 0) * KDET * 2;
  const double* dd = dets + ((size_t)b * 2 + 1) * KDET * 2;
  double t[KDET], s[KDET], m = -1e300;
  #pragma unroll
  for (int k = 0; k < KDET; ++k) {
    t[k] = du[2 * k] + dd[2 * k];
    s[k] = du[2 * k + 1] * dd[2 * k + 1];
    if (t[k] > m) m = t[k];
  }
  double sum = 0.0;
  #pragma unroll
  for (int k = 0; k < KDET; ++k) {
    if (t[k] > -1e290) sum += s[k] * exp(t[k] - m);
  }
  double p  = (m > -1e290) ? exp(m) * fabs(sum) : 0.0;
  double la = log(p + 1e-30);                    // reproduce ref clamp exactly
  float phase = (sum >= 0.0) ? 0.0f : 3.14159265358979f;
  out[b]     = (float)la;
  out[B + b] = phase;
}

extern "C" void kernel_launch(void* const* d_in, const int* in_sizes, int n_in,
                              void* d_out, int out_size, void* d_ws, size_t ws_size,
                              hipStream_t stream) {
  const int*   configs = (const int*)  d_in[0];
  const float* tok     = (const float*)d_in[1];
  const float* pos     = (const float*)d_in[2];
  const float* W       = (const float*)d_in[3];
  const float* bv      = (const float*)d_in[4];

  float*  wsf  = (float*)d_ws;
  float*  T    = wsf;                       // 4*400 floats
  float*  P    = wsf + 4 * NTAB;            // 144*400 floats
  double* dets = (double*)(wsf + TP_FLOATS);  // 236800B offset, 8-aligned
  const int B = in_sizes[0] / NSITE;        // total ws: ~499KB

  tp_kernel<<<(148 * NTAB + 255) / 256, 256, 0, stream>>>(tok, pos, W, bv, T, P);
  dim3 grid(B, 2);
  det_kernel<<<grid, 256, 0, stream>>>(configs, T, P, dets);
  combine_kernel<<<(B + 255) / 256, 256, 0, stream>>>(dets, (float*)d_out, B);
}